// Round 14
// baseline (28.394 us; speedup 1.0000x reference)
//
#include <hip/hip_runtime.h>
#include <math.h>

// LogicConv2d, single fused PERSISTENT kernel.
//
// 1280 persistent blocks (5/CU; LDS 28.5 KB) x 256 threads, grid-striding
// over 2048 tiles of 64 batches. Prologue: wave 3 builds the weight table
// in LDS (softmax(sel_a), softmax(sel_b), 16-way mix collapsed to
// out = Cab*ab + Ca*a + Cb*b + C0; tab[81][24] = sa[9] sb[9] C[4] pad)
// while waves 0-2 issue the first tile's global->LDS DMA — the build hides
// under the DMA latency and is paid once per block (amortized ~1.6 tiles).
// This removes the prep kernel AND its graph-node serialization (R13's
// lesson: per-replay serial overhead, not pipe utilization, is the cost —
// all pipes <25% busy, working set L3-resident).
//
// Per tile: DMA stage -> barrier -> compute (wave w<3 owns units
// 27w..27w+26 == patch-row w; 27 inputs hoisted to regs; weights via
// wave-uniform ds_read_b128 broadcast; fully unrolled; results overwrite
// the tile slice in place) -> barrier -> coalesced float4 writeback ->
// barrier (protects LDS from next iteration's DMA).

#define NB      131072
#define NUNITS  81
#define BPB     64             // batches per tile
#define THREADS 256
#define NTILES  (NB / BPB)     // 2048
#define PBLK    1280           // persistent blocks = 5 per CU x 256 CUs
#define REC     24             // floats per unit record (96 B)
#define CHUNKS  (BPB * 81 / 4) // 1296 float4 per tile

typedef __attribute__((address_space(1))) const void GAS;
typedef __attribute__((address_space(3))) void LAS;

__global__ __launch_bounds__(THREADS, 5)
void logic_fused_persistent(const float* __restrict__ x,
                            const float* __restrict__ sa_logits,
                            const float* __restrict__ sb_logits,
                            const float* __restrict__ op_logits,
                            float* __restrict__ out)
{
    __shared__ float s_tile[BPB * 81];     // 20736 B
    __shared__ float s_tab[NUNITS * REC];  //  7776 B

    const int tid   = threadIdx.x;
    const int lane  = tid & 63;
    const int wavei = __builtin_amdgcn_readfirstlane(tid >> 6);

    const int t0 = blockIdx.x;             // first tile

    // ---- prologue: waves 0-2 issue first DMA; wave 3 builds the table ----
    if (wavei < 3) {
        const float4* gsrc = (const float4*)(x + (size_t)t0 * BPB * 81);
        const int t3 = wavei * 64 + lane;              // 0..191
        #pragma unroll
        for (int k = 0; k < 7; ++k) {
            const int j = t3 + k * 192;
            if (j < CHUNKS) {
                // wave-uniform LDS base; hardware adds lane*16
                float* lbase = s_tile + (size_t)(k * 192 + wavei * 64) * 4;
                __builtin_amdgcn_global_load_lds((GAS*)(gsrc + j), (LAS*)lbase,
                                                 16, 0, 0);
            }
        }
    } else {
        for (int u = lane; u < NUNITS; u += 64) {
            float v[9], m = -1e30f;
            #pragma unroll
            for (int i = 0; i < 9; ++i) { v[i] = sa_logits[u * 9 + i]; m = fmaxf(m, v[i]); }
            float s = 0.f;
            #pragma unroll
            for (int i = 0; i < 9; ++i) { v[i] = expf(v[i] - m); s += v[i]; }
            const float r = 1.f / s;
            #pragma unroll
            for (int i = 0; i < 9; ++i) s_tab[u * REC + i] = v[i] * r;
        }
        for (int u = lane; u < NUNITS; u += 64) {
            float v[9], m = -1e30f;
            #pragma unroll
            for (int i = 0; i < 9; ++i) { v[i] = sb_logits[u * 9 + i]; m = fmaxf(m, v[i]); }
            float s = 0.f;
            #pragma unroll
            for (int i = 0; i < 9; ++i) { v[i] = expf(v[i] - m); s += v[i]; }
            const float r = 1.f / s;
            #pragma unroll
            for (int i = 0; i < 9; ++i) s_tab[u * REC + 9 + i] = v[i] * r;
        }
        for (int u = lane; u < NUNITS; u += 64) {
            float v[16], m = -1e30f;
            #pragma unroll
            for (int i = 0; i < 16; ++i) { v[i] = op_logits[u * 16 + i]; m = fmaxf(m, v[i]); }
            float s = 0.f;
            #pragma unroll
            for (int i = 0; i < 16; ++i) { v[i] = expf(v[i] - m); s += v[i]; }
            const float r = 1.f / s;
            #pragma unroll
            for (int i = 0; i < 16; ++i) v[i] *= r;
            const float cab = v[1] - v[2] - v[4] - 2.f*v[6] - v[7] + v[8] + 2.f*v[9]
                            + v[11] + v[13] - v[14];
            const float ca  = v[2] + v[3] + v[6] + v[7] - v[8] - v[9] - v[12] - v[13];
            const float cb  = v[4] + v[5] + v[6] + v[7] - v[8] - v[9] - v[10] - v[11];
            const float c0  = v[8] + v[9] + v[10] + v[11] + v[12] + v[13] + v[14] + v[15];
            s_tab[u * REC + 18] = cab;
            s_tab[u * REC + 19] = ca;
            s_tab[u * REC + 20] = cb;
            s_tab[u * REC + 21] = c0;
        }
    }

    for (int t = t0; t < NTILES; t += PBLK) {
        const size_t b0 = (size_t)t * BPB;

        // stage (already issued for the first iteration in the prologue)
        if (t != t0) {
            const float4* gsrc = (const float4*)(x + b0 * 81);
            #pragma unroll
            for (int k = 0; k < 6; ++k) {
                const int j = tid + k * THREADS;
                if (j < CHUNKS) {
                    float* lbase = s_tile + (size_t)(k * THREADS + wavei * 64) * 4;
                    __builtin_amdgcn_global_load_lds((GAS*)(gsrc + j), (LAS*)lbase,
                                                     16, 0, 0);
                }
            }
        }
        __syncthreads();

        // ---- compute: wave w<3 owns units 27w..27w+26 (== patch-row w) ----
        if (wavei < 3) {
            float* my = s_tile + lane * 81 + wavei * 27;    // read == write slice

            float in[27];                                    // img rows 3w..3w+2
            #pragma unroll
            for (int j = 0; j < 27; ++j) in[j] = my[j];

            const float* __restrict__ wt = s_tab + wavei * 27 * REC;  // uniform

            #pragma unroll
            for (int j = 0; j < 27; ++j) {                   // unit u = 27*wavei+j
                const int q = j / 9;                         // patch col within row
                const float* __restrict__ wr = wt + j * REC; // broadcast ds_read
                float a = 0.f, b = 0.f;
                #pragma unroll
                for (int i = 0; i < 9; ++i) {
                    const float xi = in[q * 3 + (i / 3) * 9 + (i % 3)];
                    a = fmaf(xi, wr[i],     a);
                    b = fmaf(xi, wr[9 + i], b);
                }
                my[j] = fmaf(wr[18], a * b, fmaf(wr[19], a, fmaf(wr[20], b, wr[21])));
            }
        }

        __syncthreads();

        // ---- coalesced writeback, all 4 waves ----
        {
            const float4* s4 = (const float4*)s_tile;
            float4* gdst = (float4*)(out + b0 * 81);
            #pragma unroll
            for (int k = 0; k < 6; ++k) {
                const int j = tid + k * THREADS;
                if (j < CHUNKS) gdst[j] = s4[j];
            }
        }

        // protect the LDS tile from the next iteration's DMA
        __syncthreads();
    }
}

extern "C" void kernel_launch(void* const* d_in, const int* in_sizes, int n_in,
                              void* d_out, int out_size, void* d_ws, size_t ws_size,
                              hipStream_t stream)
{
    const float* x  = (const float*)d_in[0];
    const float* sa = (const float*)d_in[1];
    const float* sb = (const float*)d_in[2];
    const float* op = (const float*)d_in[3];
    float* outp = (float*)d_out;

    logic_fused_persistent<<<PBLK, THREADS, 0, stream>>>(x, sa, sb, op, outp);
}

// Round 16
// 26.006 us; speedup vs baseline: 1.0918x; 1.0918x over previous
//
#include <hip/hip_runtime.h>
#include <math.h>

// LogicConv2d, prep + PERSISTENT grid-stride main + non-temporal writeback.
//
// prep (1 block): softmax(sel_a), softmax(sel_b), collapse 16-way mix to
//   out = Cab*ab + Ca*a + Cb*b + C0. tab[81][24] floats in d_ws, readable as
//   6 aligned float4 per unit: q0=sa[0:4] q1=sa[4:8] q2={sa8,sb0,sb1,sb2}
//   q3=sb[3:7] q4={sb7,sb8,Cab,Ca} q5={Cb,C0,-,-}.
//
// main: 1792 persistent blocks (7/CU = LDS residency limit) x 256 threads;
//   each loops tiles t = bid, bid+1792 (64 batches/tile): global_load_lds
//   DMA staging -> barrier -> compute (wave w<3 owns units 27w..27w+26 ==
//   patch-row w; 27 inputs in regs; weights via wave-uniform float4 loads;
//   fully unrolled; in-place tile) -> barrier -> coalesced writeback with
//   NON-TEMPORAL stores (native ext_vector_type for the builtin) -> barrier.
//
// R15 change (only one vs R13): nt writeback. Counters show WRITE_SIZE =
// full 41.5 MB hits HBM every replay while FETCH_SIZE = 21 MB means the
// write stream's cache allocation evicts x from L3. nt stores stop
// polluting L2/L3 -> x stays L3-resident -> HBM fetch ~0.

#define NB      131072
#define NUNITS  81
#define BPB     64             // batches per tile
#define THREADS 256
#define NTILES  (NB / BPB)     // 2048
#define PBLK    1792           // persistent blocks = 7 per CU x 256 CUs
#define REC     24             // floats per unit record (96 B)
#define CHUNKS  (BPB * 81 / 4) // 1296 float4 per tile

typedef __attribute__((address_space(1))) const void GAS;
typedef __attribute__((address_space(3))) void LAS;
typedef float vfloat4 __attribute__((ext_vector_type(4)));  // clang vector: nt-builtin-compatible

__global__ __launch_bounds__(256)
void logic_prep_kernel(const float* __restrict__ sa_logits,
                       const float* __restrict__ sb_logits,
                       const float* __restrict__ op_logits,
                       float* __restrict__ tab)
{
    const int tid = threadIdx.x;
    if (tid < 81) {
        const int u = tid;
        float v[9], m = -1e30f;
        #pragma unroll
        for (int i = 0; i < 9; ++i) { v[i] = sa_logits[u * 9 + i]; m = fmaxf(m, v[i]); }
        float s = 0.f;
        #pragma unroll
        for (int i = 0; i < 9; ++i) { v[i] = expf(v[i] - m); s += v[i]; }
        const float r = 1.f / s;
        #pragma unroll
        for (int i = 0; i < 9; ++i) tab[u * REC + i] = v[i] * r;
    } else if (tid < 162) {
        const int u = tid - 81;
        float v[9], m = -1e30f;
        #pragma unroll
        for (int i = 0; i < 9; ++i) { v[i] = sb_logits[u * 9 + i]; m = fmaxf(m, v[i]); }
        float s = 0.f;
        #pragma unroll
        for (int i = 0; i < 9; ++i) { v[i] = expf(v[i] - m); s += v[i]; }
        const float r = 1.f / s;
        #pragma unroll
        for (int i = 0; i < 9; ++i) tab[u * REC + 9 + i] = v[i] * r;
    } else if (tid < 243) {
        const int u = tid - 162;
        float v[16], m = -1e30f;
        #pragma unroll
        for (int i = 0; i < 16; ++i) { v[i] = op_logits[u * 16 + i]; m = fmaxf(m, v[i]); }
        float s = 0.f;
        #pragma unroll
        for (int i = 0; i < 16; ++i) { v[i] = expf(v[i] - m); s += v[i]; }
        const float r = 1.f / s;
        #pragma unroll
        for (int i = 0; i < 16; ++i) v[i] *= r;
        const float cab = v[1] - v[2] - v[4] - 2.f*v[6] - v[7] + v[8] + 2.f*v[9]
                        + v[11] + v[13] - v[14];
        const float ca  = v[2] + v[3] + v[6] + v[7] - v[8] - v[9] - v[12] - v[13];
        const float cb  = v[4] + v[5] + v[6] + v[7] - v[8] - v[9] - v[10] - v[11];
        const float c0  = v[8] + v[9] + v[10] + v[11] + v[12] + v[13] + v[14] + v[15];
        tab[u * REC + 18] = cab;
        tab[u * REC + 19] = ca;
        tab[u * REC + 20] = cb;
        tab[u * REC + 21] = c0;
    }
}

__global__ __launch_bounds__(THREADS, 7)
void logic_main_kernel(const float* __restrict__ x,
                       const float* __restrict__ tab,
                       float* __restrict__ out)
{
    __shared__ float s_tile[BPB * 81];     // 20736 B — the only LDS

    const int tid   = threadIdx.x;
    const int lane  = tid & 63;
    const int wavei = __builtin_amdgcn_readfirstlane(tid >> 6);

    for (int t = blockIdx.x; t < NTILES; t += PBLK) {
        const size_t b0 = (size_t)t * BPB;

        // ---- stage input tile via global->LDS DMA ----
        {
            const float4* gsrc = (const float4*)(x + b0 * 81);
            #pragma unroll
            for (int k = 0; k < 6; ++k) {
                const int j = tid + k * THREADS;
                if (j < CHUNKS) {
                    // wave-uniform LDS base; hardware adds lane*16
                    float* lbase = s_tile + (size_t)(k * THREADS + wavei * 64) * 4;
                    __builtin_amdgcn_global_load_lds((GAS*)(gsrc + j), (LAS*)lbase,
                                                     16, 0, 0);
                }
            }
        }
        __syncthreads();

        // ---- compute: wave w<3 owns units 27w..27w+26 (== patch-row w) ----
        if (wavei < 3) {
            float* my = s_tile + lane * 81 + wavei * 27;    // read == write slice

            float in[27];                                    // img rows 3w..3w+2
            #pragma unroll
            for (int j = 0; j < 27; ++j) in[j] = my[j];

            const float4* __restrict__ wt4 =
                (const float4*)(tab + (size_t)wavei * 27 * REC);  // uniform base

            #pragma unroll
            for (int j = 0; j < 27; ++j) {                   // unit u = 27*wavei+j
                const int q = j / 9;                         // patch col within row
                const float4 q0 = wt4[j * 6 + 0];
                const float4 q1 = wt4[j * 6 + 1];
                const float4 q2 = wt4[j * 6 + 2];
                const float4 q3 = wt4[j * 6 + 3];
                const float4 q4 = wt4[j * 6 + 4];
                const float4 q5 = wt4[j * 6 + 5];
                const float wa[9] = { q0.x, q0.y, q0.z, q0.w, q1.x, q1.y, q1.z, q1.w, q2.x };
                const float wb[9] = { q2.y, q2.z, q2.w, q3.x, q3.y, q3.z, q3.w, q4.x, q4.y };
                float a = 0.f, b = 0.f;
                #pragma unroll
                for (int i = 0; i < 9; ++i) {
                    const float xi = in[q * 3 + (i / 3) * 9 + (i % 3)];
                    a = fmaf(xi, wa[i], a);
                    b = fmaf(xi, wb[i], b);
                }
                // q4.z=Cab q4.w=Ca q5.x=Cb q5.y=C0
                my[j] = fmaf(q4.z, a * b, fmaf(q4.w, a, fmaf(q5.x, b, q5.y)));
            }
        }

        __syncthreads();

        // ---- coalesced writeback, all 4 waves, NON-TEMPORAL stores ----
        {
            const vfloat4* s4 = (const vfloat4*)s_tile;
            vfloat4* gdst = (vfloat4*)(out + b0 * 81);
            #pragma unroll
            for (int k = 0; k < 6; ++k) {
                const int j = tid + k * THREADS;
                if (j < CHUNKS) __builtin_nontemporal_store(s4[j], gdst + j);
            }
        }

        // protect the LDS tile from the next iteration's DMA
        __syncthreads();
    }
}

extern "C" void kernel_launch(void* const* d_in, const int* in_sizes, int n_in,
                              void* d_out, int out_size, void* d_ws, size_t ws_size,
                              hipStream_t stream)
{
    const float* x  = (const float*)d_in[0];
    const float* sa = (const float*)d_in[1];
    const float* sb = (const float*)d_in[2];
    const float* op = (const float*)d_in[3];
    float* tab  = (float*)d_ws;             // 81*24*4 = 7776 B
    float* outp = (float*)d_out;

    logic_prep_kernel<<<1, 256, 0, stream>>>(sa, sb, op, tab);
    logic_main_kernel<<<PBLK, THREADS, 0, stream>>>(x, tab, outp);
}